// Round 6
// baseline (236.519 us; speedup 1.0000x reference)
//
#include <hip/hip_runtime.h>
#include <math.h>

// DeformAtten2D: B=4, H=W=C=128.
// R6: 4 launches. k_off also emits x_bf (k_cvt deleted; weights cvt folded
// into k_wprep). k_fused2: barriers 9->3 — q GEMM reads A-frags direct from
// global and overlaps the gather->LDS drain; k&v GEMMs fused (shared A
// frags); all epilogues write packed 8B short4 direct to global (no LDS
// staging). k_attn3 unchanged. GEMM numerics identical to R5.
#define IMG 16384   // 128*128

typedef short short4v __attribute__((ext_vector_type(4)));
typedef short short8  __attribute__((ext_vector_type(8)));
typedef float floatx4 __attribute__((ext_vector_type(4)));

__device__ __forceinline__ float4 ld4(const float* p) {
    return *reinterpret_cast<const float4*>(p);
}
__device__ __forceinline__ short f2bf(float f) {
    union { float f; unsigned u; } v; v.f = f;
    unsigned r = v.u + 0x7fffu + ((v.u >> 16) & 1u);   // RNE
    return (short)(r >> 16);
}
__device__ __forceinline__ float bf2f(short s) {
    union { unsigned u; float f; } v;
    v.u = ((unsigned)(unsigned short)s) << 16;
    return v.f;
}

// ---------------------------------------------------------------------------
// Kernel 1: blocks 0..49: o50=(t,tap) weight folding (W2, cst, b_eff).
//           blocks 50..81: [Wq|Wk|Wv|Wo] -> bf16 wbf.
// ---------------------------------------------------------------------------
__launch_bounds__(256)
__global__ void k_wprep(const float* __restrict__ Wc1, const float* __restrict__ Wc2,
                        const float* __restrict__ bc1, const float* __restrict__ Wq,
                        const float* __restrict__ bq, const float* __restrict__ Wk,
                        const float* __restrict__ Wv, const float* __restrict__ Wo,
                        float* __restrict__ W2, float* __restrict__ cst,
                        float* __restrict__ b_eff, short* __restrict__ wbf) {
    const int t = threadIdx.x;
    if (blockIdx.x >= 50) {                  // weight bf16 conversion
        int i = (blockIdx.x - 50) * 256 + t;  // < 8192
        int base = i * 8;
        int sel = base >> 14, off = base & 16383;
        const float* s = (sel == 0) ? Wq : (sel == 1) ? Wk : (sel == 2) ? Wv : Wo;
        float4 a = ld4(s + off), b = ld4(s + off + 4);
        short8 o;
        o[0] = f2bf(a.x); o[1] = f2bf(a.y); o[2] = f2bf(a.z); o[3] = f2bf(a.w);
        o[4] = f2bf(b.x); o[5] = f2bf(b.y); o[6] = f2bf(b.z); o[7] = f2bf(b.w);
        *reinterpret_cast<short8*>(wbf + base) = o;
        return;
    }
    __shared__ float U[128];
    __shared__ float red[256];
    __shared__ float wc2[128];
    __shared__ float bql[128];
    const int tt = blockIdx.x;               // 0..49
    const int tch = tt / 25, tap = tt % 25;
    if (t < 128) { wc2[t] = Wc2[tch * 128 + t]; bql[t] = bq[t]; }
    __syncthreads();
    const int c = t & 127, half = t >> 7;
    float p = 0.f;
    for (int o = half * 64; o < half * 64 + 64; ++o)
        p += wc2[o] * Wc1[(o * 128 + c) * 25 + tap];
    red[half * 128 + c] = p;
    __syncthreads();
    if (t < 128) U[t] = red[t] + red[128 + t];
    __syncthreads();
    float p2 = 0.f;
    for (int cc = half * 64; cc < half * 64 + 64; ++cc)
        p2 += U[cc] * Wq[cc * 128 + c];
    red[half * 128 + c] = p2;
    __syncthreads();
    if (t < 128) W2[tt * 128 + t] = red[t] + red[128 + t];
    if (t < 128) red[t] = U[t] * bql[t];
    __syncthreads();
    if (t == 0) {
        float s = 0.f;
        for (int j = 0; j < 128; ++j) s += red[j];
        cst[tt] = s;
    }
    if (tap == 0) {
        __syncthreads();
        if (t < 128) red[t] = wc2[t] * bc1[t];
        __syncthreads();
        if (t == 0) {
            float s = 0.f;
            for (int j = 0; j < 128; ++j) s += red[j];
            b_eff[tch] = s;
        }
    }
}

// ---------------------------------------------------------------------------
// Kernel 2: P[b][o50][pix] = W2[o50]·x[pix] + cst[o50]  (fp32 — accuracy)
//           + emits x_bf (each x element passes through exactly once).
// ---------------------------------------------------------------------------
__launch_bounds__(256)
__global__ void k_off(const float* __restrict__ x, const float* __restrict__ W2,
                      const float* __restrict__ cst, float* __restrict__ P,
                      short* __restrict__ x_bf) {
    __shared__ float Wlds[128 * 68];
    __shared__ float Alds[32 * 68];
    const int t = threadIdx.x;
    const int pg = t & 15, og = t >> 4;
    const int p0 = blockIdx.x * 64;
    const int b = p0 >> 14, pix0 = p0 & (IMG - 1);

    for (int id = t; id < 128 * 64; id += 256) {
        int k = id >> 6, o = id & 63;
        Wlds[k * 68 + o] = (o < 50) ? W2[o * 128 + k] : 0.f;
    }
    float acc[4][4];
#pragma unroll
    for (int i = 0; i < 4; ++i)
#pragma unroll
        for (int j = 0; j < 4; ++j) acc[i][j] = 0.f;

    for (int kc = 0; kc < 128; kc += 32) {
        __syncthreads();
#pragma unroll
        for (int rep = 0; rep < 2; ++rep) {
            int id = rep * 256 + t;
            int m = id >> 3, k4 = (id & 7) * 4;
            float4 v = ld4(x + (size_t)(p0 + m) * 128 + kc + k4);
            Alds[(k4 + 0) * 68 + m] = v.x;
            Alds[(k4 + 1) * 68 + m] = v.y;
            Alds[(k4 + 2) * 68 + m] = v.z;
            Alds[(k4 + 3) * 68 + m] = v.w;
            short4v s = {f2bf(v.x), f2bf(v.y), f2bf(v.z), f2bf(v.w)};
            *reinterpret_cast<short4v*>(x_bf + (size_t)(p0 + m) * 128 + kc + k4) = s;
        }
        __syncthreads();
#pragma unroll
        for (int k = 0; k < 32; ++k) {
            float4 a = *reinterpret_cast<float4*>(&Alds[k * 68 + 4 * pg]);
            float4 wv = *reinterpret_cast<float4*>(&Wlds[(kc + k) * 68 + 4 * og]);
            float av[4] = {a.x, a.y, a.z, a.w};
            float wf[4] = {wv.x, wv.y, wv.z, wv.w};
#pragma unroll
            for (int i = 0; i < 4; ++i)
#pragma unroll
                for (int j = 0; j < 4; ++j)
                    acc[i][j] = fmaf(av[i], wf[j], acc[i][j]);
        }
    }
    __syncthreads();
#pragma unroll
    for (int j = 0; j < 4; ++j) {
        int o = 4 * og + j;
        float c = (o < 50) ? cst[o] : 0.f;
        *reinterpret_cast<float4*>(&Wlds[o * 68 + 4 * pg]) =
            make_float4(acc[0][j] + c, acc[1][j] + c, acc[2][j] + c, acc[3][j] + c);
    }
    __syncthreads();
    for (int id = t; id < 50 * 16; id += 256) {
        int o = id >> 4, px4 = (id & 15) * 4;
        float4 v = *reinterpret_cast<float4*>(&Wlds[o * 68 + px4]);
        *reinterpret_cast<float4*>(P + ((size_t)(b * 50 + o)) * IMG + pix0 + px4) = v;
    }
}

// ---------------------------------------------------------------------------
// Kernel 3: FUSED per (b,h) row, 3 barriers total:
//   A: P rows -> conv shift-add -> tanh*5 offsets (LDS)
//   B: bilinear gather -> xsT (LDS); then q GEMM (global A-frags) overlaps
//      the gather drain; barrier; fused k&v GEMM from xsT.
//   All GEMM epilogues: packed 8B short4 direct-to-global (C rows contiguous).
// LDS: rowsP 26400 + xsT 34816 + offs 1024 = 62240 B.
// ---------------------------------------------------------------------------
__launch_bounds__(256, 2)
__global__ void k_fused2(const float* __restrict__ P, const float* __restrict__ b_eff,
                         const short* __restrict__ x_bf, const short* __restrict__ wbf,
                         const float* __restrict__ bq, const float* __restrict__ bk,
                         const float* __restrict__ bv, const float* __restrict__ rel,
                         short* __restrict__ q_bf, short* __restrict__ k_bf,
                         short* __restrict__ v_bf) {
    __shared__ __align__(16) char smem[62240];
    float* rowsP  = (float*)smem;                // 50*132*4 = 26400 B
    short* xsT    = (short*)(smem + 26400);      // 128*136*2 = 34816 B
    float* offs_l = (float*)(smem + 61216);      // 1024 B

    const int t = threadIdx.x;
    const int w = t >> 6, l = t & 63, l15 = l & 15, quad = l >> 4;
    const int mh = w >> 1, nh = w & 1;
    const int bh = blockIdx.x;
    const int b = bh >> 7, h = bh & 127;

    // ---- Phase A: P rows (5-row halo), 25-tap shift-add, tanh*5 ----
    for (int id = t; id < 1600; id += 256) {
        int o = id >> 5, q4 = (id & 31) * 4;
        int di = (o % 25) / 5;
        int r = h + di - 2;
        float4 v = make_float4(0.f, 0.f, 0.f, 0.f);
        if (r >= 0 && r < 128)
            v = ld4(P + ((size_t)(b * 50 + o)) * IMG + r * 128 + q4);
        *reinterpret_cast<float4*>(&rowsP[o * 132 + q4]) = v;
    }
    __syncthreads();
    {
        int wp = t & 127, tc = t >> 7;
        float acc = 0.f;
#pragma unroll
        for (int di = 0; di < 5; ++di)
#pragma unroll
            for (int dj = 0; dj < 5; ++dj) {
                int wj = wp + dj - 2;
                if (wj >= 0 && wj < 128)
                    acc += rowsP[(tc * 25 + di * 5 + dj) * 132 + wj];
            }
        offs_l[tc * 128 + wp] = tanhf(acc + b_eff[tc]) * 5.0f;
    }
    __syncthreads();   // offs ready

    // ---- Phase B: bilinear gather -> xsT (no barrier yet) ----
    for (int id = t; id < 2048; id += 256) {
        int px = id >> 4, c8 = id & 15;
        float ox = offs_l[px];
        float oy = offs_l[128 + px];
        float xg = ((float)px + ox) * (128.0f / 127.0f) - 0.5f;
        float yg = ((float)h  + oy) * (128.0f / 127.0f) - 0.5f;
        float x0f = floorf(xg), y0f = floorf(yg);
        float fx = xg - x0f, fy = yg - y0f;
        int x0 = (int)x0f, y0 = (int)y0f;
        float s[8];
#pragma unroll
        for (int r = 0; r < 8; ++r) s[r] = 0.f;
#pragma unroll
        for (int tap = 0; tap < 4; ++tap) {
            int xi = x0 + (tap & 1), yi = y0 + (tap >> 1);
            float wgt = ((tap & 1) ? fx : 1.f - fx) * ((tap >> 1) ? fy : 1.f - fy);
            if (xi >= 0 && xi < 128 && yi >= 0 && yi < 128) {
                short8 v = *reinterpret_cast<const short8*>(
                    x_bf + (((size_t)(b * 128 + yi)) * 128 + xi) * 128 + c8 * 8);
#pragma unroll
                for (int r = 0; r < 8; ++r) s[r] = fmaf(wgt, bf2f(v[r]), s[r]);
            }
        }
        short8 o;
#pragma unroll
        for (int r = 0; r < 8; ++r) o[r] = f2bf(s[r]);
        *reinterpret_cast<short8*>(&xsT[px * 136 + c8 * 8]) = o;
    }

    // ---- q GEMM: A-frags direct from global x row (overlaps gather drain) ----
    {
        const short* xr = x_bf + ((size_t)(b * 128 + h)) * 128 * 128;
        floatx4 acc[4][4];
#pragma unroll
        for (int im = 0; im < 4; ++im)
#pragma unroll
            for (int in = 0; in < 4; ++in)
                acc[im][in] = (floatx4){0.f, 0.f, 0.f, 0.f};
#pragma unroll
        for (int kc = 0; kc < 128; kc += 32) {
            short8 af[4], bf_[4];
#pragma unroll
            for (int im = 0; im < 4; ++im)
                af[im] = *reinterpret_cast<const short8*>(
                    xr + (mh * 64 + im * 16 + l15) * 128 + kc + quad * 8);
#pragma unroll
            for (int in = 0; in < 4; ++in)
                bf_[in] = *reinterpret_cast<const short8*>(
                    wbf + (nh * 64 + in * 16 + l15) * 128 + kc + quad * 8);
#pragma unroll
            for (int im = 0; im < 4; ++im)
#pragma unroll
                for (int in = 0; in < 4; ++in)
                    acc[im][in] = __builtin_amdgcn_mfma_f32_16x16x32_bf16(
                        af[im], bf_[in], acc[im][in], 0, 0, 0);
        }
#pragma unroll
        for (int in = 0; in < 4; ++in) {
            int o = nh * 64 + in * 16 + l15;
            float bb = bq[o];
#pragma unroll
            for (int im = 0; im < 4; ++im) {
                int px0 = mh * 64 + im * 16 + quad * 4;
                short4v s = {f2bf(acc[im][in][0] + bb), f2bf(acc[im][in][1] + bb),
                             f2bf(acc[im][in][2] + bb), f2bf(acc[im][in][3] + bb)};
                *reinterpret_cast<short4v*>(
                    q_bf + ((size_t)(b * 128 + o)) * IMG + h * 128 + px0) = s;
            }
        }
    }
    __syncthreads();   // xsT complete

    // ---- fused k & v GEMMs (shared A-frags from xsT) ----
    {
        floatx4 ak[4][4], av[4][4];
#pragma unroll
        for (int im = 0; im < 4; ++im)
#pragma unroll
            for (int in = 0; in < 4; ++in) {
                ak[im][in] = (floatx4){0.f, 0.f, 0.f, 0.f};
                av[im][in] = (floatx4){0.f, 0.f, 0.f, 0.f};
            }
#pragma unroll
        for (int kc = 0; kc < 128; kc += 32) {
            short8 af[4], bk_[4], bv_[4];
#pragma unroll
            for (int im = 0; im < 4; ++im)
                af[im] = *reinterpret_cast<const short8*>(
                    &xsT[(mh * 64 + im * 16 + l15) * 136 + kc + quad * 8]);
#pragma unroll
            for (int in = 0; in < 4; ++in) {
                bk_[in] = *reinterpret_cast<const short8*>(
                    wbf + 16384 + (nh * 64 + in * 16 + l15) * 128 + kc + quad * 8);
                bv_[in] = *reinterpret_cast<const short8*>(
                    wbf + 32768 + (nh * 64 + in * 16 + l15) * 128 + kc + quad * 8);
            }
#pragma unroll
            for (int im = 0; im < 4; ++im)
#pragma unroll
                for (int in = 0; in < 4; ++in) {
                    ak[im][in] = __builtin_amdgcn_mfma_f32_16x16x32_bf16(
                        af[im], bk_[in], ak[im][in], 0, 0, 0);
                    av[im][in] = __builtin_amdgcn_mfma_f32_16x16x32_bf16(
                        af[im], bv_[in], av[im][in], 0, 0, 0);
                }
        }
#pragma unroll
        for (int in = 0; in < 4; ++in) {
            int o = nh * 64 + in * 16 + l15;
            float bbk = bk[o];
            float bbv = bv[o] + rel[o * 128 + h];
#pragma unroll
            for (int im = 0; im < 4; ++im) {
                int px0 = mh * 64 + im * 16 + quad * 4;
                size_t base = ((size_t)(b * 128 + o)) * IMG + h * 128 + px0;
                short4v sk = {f2bf(ak[im][in][0] + bbk), f2bf(ak[im][in][1] + bbk),
                              f2bf(ak[im][in][2] + bbk), f2bf(ak[im][in][3] + bbk)};
                short4v sv = {f2bf(av[im][in][0] + bbv), f2bf(av[im][in][1] + bbv),
                              f2bf(av[im][in][2] + bbv), f2bf(av[im][in][3] + bbv)};
                *reinterpret_cast<short4v*>(k_bf + base) = sk;
                *reinterpret_cast<short4v*>(v_bf + base) = sv;
            }
        }
    }
}

// ---------------------------------------------------------------------------
// Kernel 4: MFMA attention, register-shuffle softmax, fused output projection.
// ---------------------------------------------------------------------------
__launch_bounds__(256)
__global__ void k_attn3(const short* __restrict__ q_bf, const short* __restrict__ k_bf,
                        const short* __restrict__ v_bf, const short* __restrict__ WoB,
                        const float* __restrict__ bo, float* __restrict__ outp) {
    __shared__ __align__(16) short Pb[128 * 136];    // P bf16; then O bf16
    __shared__ __align__(16) short vT[128 * 136];    // v transposed
    __shared__ float redm[2 * 128];
    __shared__ float reds[2 * 128];

    const int t = threadIdx.x;
    const int w = t >> 6, l = t & 63, l15 = l & 15, quad = l >> 4;
    const int mh = w >> 1, nh = w & 1;
    const size_t hb = (size_t)blockIdx.x * IMG;
    const short* qp = q_bf + hb;
    const short* kp = k_bf + hb;
    const short* vp = v_bf + hb;

    for (int id = t; id < 2048; id += 256) {
        int j = id >> 4, seg = id & 15;
        short8 v8 = *reinterpret_cast<const short8*>(vp + j * 128 + seg * 8);
#pragma unroll
        for (int r = 0; r < 8; ++r)
            vT[(seg * 8 + r) * 136 + j] = v8[r];
    }

    floatx4 acc[4][4];
#pragma unroll
    for (int im = 0; im < 4; ++im)
#pragma unroll
        for (int in = 0; in < 4; ++in)
            acc[im][in] = (floatx4){0.f, 0.f, 0.f, 0.f};

#pragma unroll
    for (int kc = 0; kc < 128; kc += 32) {
        short8 af[4], bf_[4];
#pragma unroll
        for (int im = 0; im < 4; ++im)
            af[im] = *reinterpret_cast<const short8*>(
                qp + (mh * 64 + im * 16 + l15) * 128 + kc + quad * 8);
#pragma unroll
        for (int in = 0; in < 4; ++in)
            bf_[in] = *reinterpret_cast<const short8*>(
                kp + (nh * 64 + in * 16 + l15) * 128 + kc + quad * 8);
#pragma unroll
        for (int im = 0; im < 4; ++im)
#pragma unroll
            for (int in = 0; in < 4; ++in)
                acc[im][in] = __builtin_amdgcn_mfma_f32_16x16x32_bf16(
                    af[im], bf_[in], acc[im][in], 0, 0, 0);
    }

    const float scale = 0.08838834764831845f;
    float mloc[4][4];
#pragma unroll
    for (int im = 0; im < 4; ++im)
#pragma unroll
        for (int r = 0; r < 4; ++r) {
            float m = acc[im][0][r];
#pragma unroll
            for (int in = 1; in < 4; ++in) m = fmaxf(m, acc[im][in][r]);
            mloc[im][r] = m;
        }
#pragma unroll
    for (int mask = 1; mask < 16; mask <<= 1)
#pragma unroll
        for (int im = 0; im < 4; ++im)
#pragma unroll
            for (int r = 0; r < 4; ++r)
                mloc[im][r] = fmaxf(mloc[im][r], __shfl_xor(mloc[im][r], mask, 64));
    if (l15 == 0) {
#pragma unroll
        for (int im = 0; im < 4; ++im)
#pragma unroll
            for (int r = 0; r < 4; ++r)
                redm[nh * 128 + mh * 64 + im * 16 + quad * 4 + r] = mloc[im][r];
    }
    __syncthreads();
    float sloc[4][4];
#pragma unroll
    for (int im = 0; im < 4; ++im)
#pragma unroll
        for (int r = 0; r < 4; ++r) {
            int row = mh * 64 + im * 16 + quad * 4 + r;
            float m = fmaxf(redm[row], redm[128 + row]);
            float ss = 0.f;
#pragma unroll
            for (int in = 0; in < 4; ++in) {
                float e = __expf((acc[im][in][r] - m) * scale);
                acc[im][in][r] = e;
                ss += e;
            }
            sloc[im][r] = ss;
        }
#pragma unroll
    for (int mask = 1; mask < 16; mask <<= 1)
#pragma unroll
        for (int im = 0; im < 4; ++im)
#pragma unroll
            for (int r = 0; r < 4; ++r)
                sloc[im][r] += __shfl_xor(sloc[im][r], mask, 64);
    if (l15 == 0) {
#pragma unroll
        for (int im = 0; im < 4; ++im)
#pragma unroll
            for (int r = 0; r < 4; ++r)
                reds[nh * 128 + mh * 64 + im * 16 + quad * 4 + r] = sloc[im][r];
    }
    __syncthreads();
#pragma unroll
    for (int im = 0; im < 4; ++im)
#pragma unroll
        for (int r = 0; r < 4; ++r) {
            int row = mh * 64 + im * 16 + quad * 4 + r;
            float inv = 1.0f / (reds[row] + reds[128 + row]);
#pragma unroll
            for (int in = 0; in < 4; ++in) {
                int col = nh * 64 + in * 16 + l15;
                Pb[row * 136 + col] = f2bf(acc[im][in][r] * inv);
            }
        }
    __syncthreads();

#pragma unroll
    for (int im = 0; im < 4; ++im)
#pragma unroll
        for (int in = 0; in < 4; ++in)
            acc[im][in] = (floatx4){0.f, 0.f, 0.f, 0.f};
#pragma unroll
    for (int kc = 0; kc < 128; kc += 32) {
        short8 af[4], bf_[4];
#pragma unroll
        for (int im = 0; im < 4; ++im)
            af[im] = *reinterpret_cast<const short8*>(
                &Pb[(mh * 64 + im * 16 + l15) * 136 + kc + quad * 8]);
#pragma unroll
        for (int in = 0; in < 4; ++in)
            bf_[in] = *reinterpret_cast<const short8*>(
                &vT[(nh * 64 + in * 16 + l15) * 136 + kc + quad * 8]);
#pragma unroll
        for (int im = 0; im < 4; ++im)
#pragma unroll
            for (int in = 0; in < 4; ++in)
                acc[im][in] = __builtin_amdgcn_mfma_f32_16x16x32_bf16(
                    af[im], bf_[in], acc[im][in], 0, 0, 0);
    }
    __syncthreads();
#pragma unroll
    for (int im = 0; im < 4; ++im)
#pragma unroll
        for (int in = 0; in < 4; ++in) {
            int col = nh * 64 + in * 16 + l15;
#pragma unroll
            for (int r = 0; r < 4; ++r) {
                int row = mh * 64 + im * 16 + quad * 4 + r;
                Pb[row * 136 + col] = f2bf(acc[im][in][r]);
            }
        }
    __syncthreads();

    float bb[4];
#pragma unroll
    for (int in = 0; in < 4; ++in) bb[in] = bo[nh * 64 + in * 16 + l15];
#pragma unroll
    for (int im = 0; im < 4; ++im)
#pragma unroll
        for (int in = 0; in < 4; ++in)
            acc[im][in] = (floatx4){0.f, 0.f, 0.f, 0.f};
#pragma unroll
    for (int kc = 0; kc < 128; kc += 32) {
        short8 af[4], bf_[4];
#pragma unroll
        for (int im = 0; im < 4; ++im)
            af[im] = *reinterpret_cast<const short8*>(
                &Pb[(mh * 64 + im * 16 + l15) * 136 + kc + quad * 8]);
#pragma unroll
        for (int in = 0; in < 4; ++in)
            bf_[in] = *reinterpret_cast<const short8*>(
                WoB + (nh * 64 + in * 16 + l15) * 128 + kc + quad * 8);
#pragma unroll
        for (int im = 0; im < 4; ++im)
#pragma unroll
            for (int in = 0; in < 4; ++in)
                acc[im][in] = __builtin_amdgcn_mfma_f32_16x16x32_bf16(
                    af[im], bf_[in], acc[im][in], 0, 0, 0);
    }
#pragma unroll
    for (int im = 0; im < 4; ++im)
#pragma unroll
        for (int in = 0; in < 4; ++in) {
            int col = nh * 64 + in * 16 + l15;
#pragma unroll
            for (int r = 0; r < 4; ++r) {
                int row = mh * 64 + im * 16 + quad * 4 + r;
                outp[hb + (size_t)row * 128 + col] = acc[im][in][r] + bb[in];
            }
        }
}

// ---------------------------------------------------------------------------
extern "C" void kernel_launch(void* const* d_in, const int* in_sizes, int n_in,
                              void* d_out, int out_size, void* d_ws, size_t ws_size,
                              hipStream_t stream) {
    const float* x   = (const float*)d_in[0];
    const float* Wq  = (const float*)d_in[2];
    const float* bq  = (const float*)d_in[3];
    const float* Wk  = (const float*)d_in[4];
    const float* bk  = (const float*)d_in[5];
    const float* Wv  = (const float*)d_in[6];
    const float* bv  = (const float*)d_in[7];
    const float* Wo  = (const float*)d_in[8];
    const float* bo  = (const float*)d_in[9];
    const float* Wc1 = (const float*)d_in[10];
    const float* bc1 = (const float*)d_in[11];
    const float* Wc2 = (const float*)d_in[12];
    const float* rel = (const float*)d_in[13];

    char* wsb = (char*)d_ws;
    short* q_bf  = (short*)(wsb);                       // 16 MB
    short* k_bf  = (short*)(wsb + 1ull * 16777216);
    short* v_bf  = (short*)(wsb + 2ull * 16777216);
    short* x_bf  = (short*)(wsb + 3ull * 16777216);
    float* P     = (float*)(wsb + 4ull * 16777216);     // 13.1 MB
    float* W2    = (float*)(wsb + 4ull * 16777216 + 13107200);
    float* cst   = W2 + 6400;
    float* b_eff = cst + 64;
    short* wbf   = (short*)(b_eff + 16);                // 4 x 16384 bf16
    float* outp  = (float*)d_out;

    hipLaunchKernelGGL(k_wprep,  dim3(82),   dim3(256), 0, stream, Wc1, Wc2, bc1, Wq, bq,
                       Wk, Wv, Wo, W2, cst, b_eff, wbf);
    hipLaunchKernelGGL(k_off,    dim3(1024), dim3(256), 0, stream, x, W2, cst, P, x_bf);
    hipLaunchKernelGGL(k_fused2, dim3(512),  dim3(256), 0, stream, P, b_eff, x_bf, wbf,
                       bq, bk, bv, rel, q_bf, k_bf, v_bf);
    hipLaunchKernelGGL(k_attn3,  dim3(512),  dim3(256), 0, stream, q_bf, k_bf, v_bf,
                       wbf + 49152, bo, outp);
}

// Round 7
// 220.337 us; speedup vs baseline: 1.0734x; 1.0734x over previous
//
#include <hip/hip_runtime.h>
#include <math.h>

// DeformAtten2D: B=4, H=W=C=128.
// R7: R6's direct-global-store epilogue REVERTED (8B scattered stores across
// 16 planes regressed 41->54us). k_fused3 = R5 staged coalesced epilogues +
// q GEMM direct-global A-frags (xrow phase gone) + fused k&v GEMMs (shared
// xsT A-frags); k+v staged into two LDS regions simultaneously -> 6 barriers.
// k_attn3: vT transpose XOR-swizzled (was 16-way bank-conflicted writes).
#define IMG 16384   // 128*128

typedef short short4v __attribute__((ext_vector_type(4)));
typedef short short8  __attribute__((ext_vector_type(8)));
typedef float floatx4 __attribute__((ext_vector_type(4)));

__device__ __forceinline__ float4 ld4(const float* p) {
    return *reinterpret_cast<const float4*>(p);
}
__device__ __forceinline__ short f2bf(float f) {
    union { float f; unsigned u; } v; v.f = f;
    unsigned r = v.u + 0x7fffu + ((v.u >> 16) & 1u);   // RNE
    return (short)(r >> 16);
}
__device__ __forceinline__ float bf2f(short s) {
    union { unsigned u; float f; } v;
    v.u = ((unsigned)(unsigned short)s) << 16;
    return v.f;
}

// ---------------------------------------------------------------------------
// Kernel 1: blocks 0..49: o50=(t,tap) weight folding (W2, cst, b_eff).
//           blocks 50..81: [Wq|Wk|Wv|Wo] -> bf16 wbf.
// ---------------------------------------------------------------------------
__launch_bounds__(256)
__global__ void k_wprep(const float* __restrict__ Wc1, const float* __restrict__ Wc2,
                        const float* __restrict__ bc1, const float* __restrict__ Wq,
                        const float* __restrict__ bq, const float* __restrict__ Wk,
                        const float* __restrict__ Wv, const float* __restrict__ Wo,
                        float* __restrict__ W2, float* __restrict__ cst,
                        float* __restrict__ b_eff, short* __restrict__ wbf) {
    const int t = threadIdx.x;
    if (blockIdx.x >= 50) {                  // weight bf16 conversion
        int i = (blockIdx.x - 50) * 256 + t;  // < 8192
        int base = i * 8;
        int sel = base >> 14, off = base & 16383;
        const float* s = (sel == 0) ? Wq : (sel == 1) ? Wk : (sel == 2) ? Wv : Wo;
        float4 a = ld4(s + off), b = ld4(s + off + 4);
        short8 o;
        o[0] = f2bf(a.x); o[1] = f2bf(a.y); o[2] = f2bf(a.z); o[3] = f2bf(a.w);
        o[4] = f2bf(b.x); o[5] = f2bf(b.y); o[6] = f2bf(b.z); o[7] = f2bf(b.w);
        *reinterpret_cast<short8*>(wbf + base) = o;
        return;
    }
    __shared__ float U[128];
    __shared__ float red[256];
    __shared__ float wc2[128];
    __shared__ float bql[128];
    const int tt = blockIdx.x;               // 0..49
    const int tch = tt / 25, tap = tt % 25;
    if (t < 128) { wc2[t] = Wc2[tch * 128 + t]; bql[t] = bq[t]; }
    __syncthreads();
    const int c = t & 127, half = t >> 7;
    float p = 0.f;
    for (int o = half * 64; o < half * 64 + 64; ++o)
        p += wc2[o] * Wc1[(o * 128 + c) * 25 + tap];
    red[half * 128 + c] = p;
    __syncthreads();
    if (t < 128) U[t] = red[t] + red[128 + t];
    __syncthreads();
    float p2 = 0.f;
    for (int cc = half * 64; cc < half * 64 + 64; ++cc)
        p2 += U[cc] * Wq[cc * 128 + c];
    red[half * 128 + c] = p2;
    __syncthreads();
    if (t < 128) W2[tt * 128 + t] = red[t] + red[128 + t];
    if (t < 128) red[t] = U[t] * bql[t];
    __syncthreads();
    if (t == 0) {
        float s = 0.f;
        for (int j = 0; j < 128; ++j) s += red[j];
        cst[tt] = s;
    }
    if (tap == 0) {
        __syncthreads();
        if (t < 128) red[t] = wc2[t] * bc1[t];
        __syncthreads();
        if (t == 0) {
            float s = 0.f;
            for (int j = 0; j < 128; ++j) s += red[j];
            b_eff[tch] = s;
        }
    }
}

// ---------------------------------------------------------------------------
// Kernel 2: P[b][o50][pix] = W2[o50]·x[pix] + cst[o50]  (fp32 — accuracy)
//           + emits x_bf (each x element passes through exactly once).
// ---------------------------------------------------------------------------
__launch_bounds__(256)
__global__ void k_off(const float* __restrict__ x, const float* __restrict__ W2,
                      const float* __restrict__ cst, float* __restrict__ P,
                      short* __restrict__ x_bf) {
    __shared__ float Wlds[128 * 68];
    __shared__ float Alds[32 * 68];
    const int t = threadIdx.x;
    const int pg = t & 15, og = t >> 4;
    const int p0 = blockIdx.x * 64;
    const int b = p0 >> 14, pix0 = p0 & (IMG - 1);

    for (int id = t; id < 128 * 64; id += 256) {
        int k = id >> 6, o = id & 63;
        Wlds[k * 68 + o] = (o < 50) ? W2[o * 128 + k] : 0.f;
    }
    float acc[4][4];
#pragma unroll
    for (int i = 0; i < 4; ++i)
#pragma unroll
        for (int j = 0; j < 4; ++j) acc[i][j] = 0.f;

    for (int kc = 0; kc < 128; kc += 32) {
        __syncthreads();
#pragma unroll
        for (int rep = 0; rep < 2; ++rep) {
            int id = rep * 256 + t;
            int m = id >> 3, k4 = (id & 7) * 4;
            float4 v = ld4(x + (size_t)(p0 + m) * 128 + kc + k4);
            Alds[(k4 + 0) * 68 + m] = v.x;
            Alds[(k4 + 1) * 68 + m] = v.y;
            Alds[(k4 + 2) * 68 + m] = v.z;
            Alds[(k4 + 3) * 68 + m] = v.w;
            short4v s = {f2bf(v.x), f2bf(v.y), f2bf(v.z), f2bf(v.w)};
            *reinterpret_cast<short4v*>(x_bf + (size_t)(p0 + m) * 128 + kc + k4) = s;
        }
        __syncthreads();
#pragma unroll
        for (int k = 0; k < 32; ++k) {
            float4 a = *reinterpret_cast<float4*>(&Alds[k * 68 + 4 * pg]);
            float4 wv = *reinterpret_cast<float4*>(&Wlds[(kc + k) * 68 + 4 * og]);
            float av[4] = {a.x, a.y, a.z, a.w};
            float wf[4] = {wv.x, wv.y, wv.z, wv.w};
#pragma unroll
            for (int i = 0; i < 4; ++i)
#pragma unroll
                for (int j = 0; j < 4; ++j)
                    acc[i][j] = fmaf(av[i], wf[j], acc[i][j]);
        }
    }
    __syncthreads();
#pragma unroll
    for (int j = 0; j < 4; ++j) {
        int o = 4 * og + j;
        float c = (o < 50) ? cst[o] : 0.f;
        *reinterpret_cast<float4*>(&Wlds[o * 68 + 4 * pg]) =
            make_float4(acc[0][j] + c, acc[1][j] + c, acc[2][j] + c, acc[3][j] + c);
    }
    __syncthreads();
    for (int id = t; id < 50 * 16; id += 256) {
        int o = id >> 4, px4 = (id & 15) * 4;
        float4 v = *reinterpret_cast<float4*>(&Wlds[o * 68 + px4]);
        *reinterpret_cast<float4*>(P + ((size_t)(b * 50 + o)) * IMG + pix0 + px4) = v;
    }
}

// ---------------------------------------------------------------------------
// Kernel 3: FUSED per (b,h) row, 6 barriers:
//   A: P rows -> conv shift-add -> tanh*5 offsets (LDS)
//   B: gather -> xsT; q GEMM (direct-global A-frags) overlaps gather drain
//   C: stage q (LDS transpose) -> coalesced write; fused k&v GEMM; stage k
//      into stg and v into xsT (dead) simultaneously; one combined write pass.
// LDS: stg/rowsP 34816 + xsT 34816 + offs 1024 = 70656 B (2 blocks/CU).
// ---------------------------------------------------------------------------
__launch_bounds__(256, 2)
__global__ void k_fused3(const float* __restrict__ P, const float* __restrict__ b_eff,
                         const short* __restrict__ x_bf, const short* __restrict__ wbf,
                         const float* __restrict__ bq, const float* __restrict__ bk,
                         const float* __restrict__ bv, const float* __restrict__ rel,
                         short* __restrict__ q_bf, short* __restrict__ k_bf,
                         short* __restrict__ v_bf) {
    __shared__ __align__(16) char smem[70656];
    float* rowsP  = (float*)smem;                // 26400 B (phase A only)
    short* stg    = (short*)smem;                // 34816 B stage (aliases rowsP)
    short* xsT    = (short*)(smem + 34816);      // 34816 B
    float* offs_l = (float*)(smem + 69632);      // 1024 B

    const int t = threadIdx.x;
    const int w = t >> 6, l = t & 63, l15 = l & 15, quad = l >> 4;
    const int mh = w >> 1, nh = w & 1;
    const int bh = blockIdx.x;
    const int b = bh >> 7, h = bh & 127;

    // ---- Phase A: P rows (5-row halo), 25-tap shift-add, tanh*5 ----
    for (int id = t; id < 1600; id += 256) {
        int o = id >> 5, q4 = (id & 31) * 4;
        int di = (o % 25) / 5;
        int r = h + di - 2;
        float4 v = make_float4(0.f, 0.f, 0.f, 0.f);
        if (r >= 0 && r < 128)
            v = ld4(P + ((size_t)(b * 50 + o)) * IMG + r * 128 + q4);
        *reinterpret_cast<float4*>(&rowsP[o * 132 + q4]) = v;
    }
    __syncthreads();                             // B1
    {
        int wp = t & 127, tc = t >> 7;
        float acc = 0.f;
#pragma unroll
        for (int di = 0; di < 5; ++di)
#pragma unroll
            for (int dj = 0; dj < 5; ++dj) {
                int wj = wp + dj - 2;
                if (wj >= 0 && wj < 128)
                    acc += rowsP[(tc * 25 + di * 5 + dj) * 132 + wj];
            }
        offs_l[tc * 128 + wp] = tanhf(acc + b_eff[tc]) * 5.0f;
    }
    __syncthreads();                             // B2: offs ready, rowsP dead

    // ---- Phase B: bilinear gather -> xsT (no barrier yet) ----
    for (int id = t; id < 2048; id += 256) {
        int px = id >> 4, c8 = id & 15;
        float ox = offs_l[px];
        float oy = offs_l[128 + px];
        float xg = ((float)px + ox) * (128.0f / 127.0f) - 0.5f;
        float yg = ((float)h  + oy) * (128.0f / 127.0f) - 0.5f;
        float x0f = floorf(xg), y0f = floorf(yg);
        float fx = xg - x0f, fy = yg - y0f;
        int x0 = (int)x0f, y0 = (int)y0f;
        float s[8];
#pragma unroll
        for (int r = 0; r < 8; ++r) s[r] = 0.f;
#pragma unroll
        for (int tap = 0; tap < 4; ++tap) {
            int xi = x0 + (tap & 1), yi = y0 + (tap >> 1);
            float wgt = ((tap & 1) ? fx : 1.f - fx) * ((tap >> 1) ? fy : 1.f - fy);
            if (xi >= 0 && xi < 128 && yi >= 0 && yi < 128) {
                short8 v = *reinterpret_cast<const short8*>(
                    x_bf + (((size_t)(b * 128 + yi)) * 128 + xi) * 128 + c8 * 8);
#pragma unroll
                for (int r = 0; r < 8; ++r) s[r] = fmaf(wgt, bf2f(v[r]), s[r]);
            }
        }
        short8 o;
#pragma unroll
        for (int r = 0; r < 8; ++r) o[r] = f2bf(s[r]);
        *reinterpret_cast<short8*>(&xsT[px * 136 + c8 * 8]) = o;
    }

    // ---- q GEMM: A-frags direct from global x row (overlaps gather drain) ----
    {
        const short* xr = x_bf + ((size_t)(b * 128 + h)) * 128 * 128;
        floatx4 acc[4][4];
#pragma unroll
        for (int im = 0; im < 4; ++im)
#pragma unroll
            for (int in = 0; in < 4; ++in)
                acc[im][in] = (floatx4){0.f, 0.f, 0.f, 0.f};
#pragma unroll
        for (int kc = 0; kc < 128; kc += 32) {
            short8 af[4], bf_[4];
#pragma unroll
            for (int im = 0; im < 4; ++im)
                af[im] = *reinterpret_cast<const short8*>(
                    xr + (mh * 64 + im * 16 + l15) * 128 + kc + quad * 8);
#pragma unroll
            for (int in = 0; in < 4; ++in)
                bf_[in] = *reinterpret_cast<const short8*>(
                    wbf + (nh * 64 + in * 16 + l15) * 128 + kc + quad * 8);
#pragma unroll
            for (int im = 0; im < 4; ++im)
#pragma unroll
                for (int in = 0; in < 4; ++in)
                    acc[im][in] = __builtin_amdgcn_mfma_f32_16x16x32_bf16(
                        af[im], bf_[in], acc[im][in], 0, 0, 0);
        }
        __syncthreads();                         // B3: xsT complete, stg free
        // stage q: stg[col(plane)][row(px)]
#pragma unroll
        for (int in = 0; in < 4; ++in) {
            int o = nh * 64 + in * 16 + l15;
            float bb = bq[o];
#pragma unroll
            for (int im = 0; im < 4; ++im) {
                int row0 = mh * 64 + im * 16 + quad * 4;
                short4v s = {f2bf(acc[im][in][0] + bb), f2bf(acc[im][in][1] + bb),
                             f2bf(acc[im][in][2] + bb), f2bf(acc[im][in][3] + bb)};
                *reinterpret_cast<short4v*>(&stg[o * 136 + row0]) = s;
            }
        }
    }
    __syncthreads();                             // B4
    // coalesced q write
    for (int id = t; id < 2048; id += 256) {
        int o = id >> 4, seg = id & 15;
        *reinterpret_cast<short8*>(
            q_bf + ((size_t)(b * 128 + o)) * IMG + h * 128 + seg * 8)
            = *reinterpret_cast<const short8*>(&stg[o * 136 + seg * 8]);
    }

    // ---- fused k & v GEMMs (shared A-frags from xsT) ----
    {
        floatx4 ak[4][4], av[4][4];
#pragma unroll
        for (int im = 0; im < 4; ++im)
#pragma unroll
            for (int in = 0; in < 4; ++in) {
                ak[im][in] = (floatx4){0.f, 0.f, 0.f, 0.f};
                av[im][in] = (floatx4){0.f, 0.f, 0.f, 0.f};
            }
#pragma unroll
        for (int kc = 0; kc < 128; kc += 32) {
            short8 af[4], bk_[4], bv_[4];
#pragma unroll
            for (int im = 0; im < 4; ++im)
                af[im] = *reinterpret_cast<const short8*>(
                    &xsT[(mh * 64 + im * 16 + l15) * 136 + kc + quad * 8]);
#pragma unroll
            for (int in = 0; in < 4; ++in) {
                bk_[in] = *reinterpret_cast<const short8*>(
                    wbf + 16384 + (nh * 64 + in * 16 + l15) * 128 + kc + quad * 8);
                bv_[in] = *reinterpret_cast<const short8*>(
                    wbf + 32768 + (nh * 64 + in * 16 + l15) * 128 + kc + quad * 8);
            }
#pragma unroll
            for (int im = 0; im < 4; ++im)
#pragma unroll
                for (int in = 0; in < 4; ++in) {
                    ak[im][in] = __builtin_amdgcn_mfma_f32_16x16x32_bf16(
                        af[im], bk_[in], ak[im][in], 0, 0, 0);
                    av[im][in] = __builtin_amdgcn_mfma_f32_16x16x32_bf16(
                        af[im], bv_[in], av[im][in], 0, 0, 0);
                }
        }
        __syncthreads();                         // B5: q-write stg reads + xsT reads done
        // stage k -> stg, v -> xsT (simultaneously)
#pragma unroll
        for (int in = 0; in < 4; ++in) {
            int o = nh * 64 + in * 16 + l15;
            float bbk = bk[o];
            float bbv = bv[o] + rel[o * 128 + h];
#pragma unroll
            for (int im = 0; im < 4; ++im) {
                int row0 = mh * 64 + im * 16 + quad * 4;
                short4v sk = {f2bf(ak[im][in][0] + bbk), f2bf(ak[im][in][1] + bbk),
                              f2bf(ak[im][in][2] + bbk), f2bf(ak[im][in][3] + bbk)};
                short4v sv = {f2bf(av[im][in][0] + bbv), f2bf(av[im][in][1] + bbv),
                              f2bf(av[im][in][2] + bbv), f2bf(av[im][in][3] + bbv)};
                *reinterpret_cast<short4v*>(&stg[o * 136 + row0]) = sk;
                *reinterpret_cast<short4v*>(&xsT[o * 136 + row0]) = sv;
            }
        }
    }
    __syncthreads();                             // B6
    // combined coalesced k+v write
    for (int id = t; id < 4096; id += 256) {
        int sel = id >> 11;
        int o = (id >> 4) & 127, seg = id & 15;
        short* dst = sel ? v_bf : k_bf;
        const short* src = sel ? xsT : stg;
        *reinterpret_cast<short8*>(
            dst + ((size_t)(b * 128 + o)) * IMG + h * 128 + seg * 8)
            = *reinterpret_cast<const short8*>(&src[o * 136 + seg * 8]);
    }
}

// ---------------------------------------------------------------------------
// Kernel 4: MFMA attention, register-shuffle softmax, fused output projection.
// vT transpose XOR-swizzled: chunk c of row d stored at c ^ (d>>3) — kills
// the 16-way bank conflict of the scalar transpose writes.
// ---------------------------------------------------------------------------
__launch_bounds__(256, 2)
__global__ void k_attn3(const short* __restrict__ q_bf, const short* __restrict__ k_bf,
                        const short* __restrict__ v_bf, const short* __restrict__ WoB,
                        const float* __restrict__ bo, float* __restrict__ outp) {
    __shared__ __align__(16) short Pb[128 * 136];    // P bf16; then O bf16
    __shared__ __align__(16) short vT[128 * 136];    // v^T, XOR-swizzled chunks
    __shared__ float redm[2 * 128];
    __shared__ float reds[2 * 128];

    const int t = threadIdx.x;
    const int w = t >> 6, l = t & 63, l15 = l & 15, quad = l >> 4;
    const int mh = w >> 1, nh = w & 1;
    const size_t hb = (size_t)blockIdx.x * IMG;
    const short* qp = q_bf + hb;
    const short* kp = k_bf + hb;
    const short* vp = v_bf + hb;

    // ---- v -> vT transpose (swizzled) ----
    for (int id = t; id < 2048; id += 256) {
        int j = id >> 4, seg = id & 15;
        short8 v8 = *reinterpret_cast<const short8*>(vp + j * 128 + seg * 8);
        int cbase = ((j >> 3) ^ seg) & 15;           // dRow>>3 == seg
        int off = j & 7;
#pragma unroll
        for (int r = 0; r < 8; ++r)
            vT[(seg * 8 + r) * 136 + cbase * 8 + off] = v8[r];
    }

    floatx4 acc[4][4];
#pragma unroll
    for (int im = 0; im < 4; ++im)
#pragma unroll
        for (int in = 0; in < 4; ++in)
            acc[im][in] = (floatx4){0.f, 0.f, 0.f, 0.f};

    // ---- Phase 1: S = q·kT (direct-global frags) ----
#pragma unroll
    for (int kc = 0; kc < 128; kc += 32) {
        short8 af[4], bf_[4];
#pragma unroll
        for (int im = 0; im < 4; ++im)
            af[im] = *reinterpret_cast<const short8*>(
                qp + (mh * 64 + im * 16 + l15) * 128 + kc + quad * 8);
#pragma unroll
        for (int in = 0; in < 4; ++in)
            bf_[in] = *reinterpret_cast<const short8*>(
                kp + (nh * 64 + in * 16 + l15) * 128 + kc + quad * 8);
#pragma unroll
        for (int im = 0; im < 4; ++im)
#pragma unroll
            for (int in = 0; in < 4; ++in)
                acc[im][in] = __builtin_amdgcn_mfma_f32_16x16x32_bf16(
                    af[im], bf_[in], acc[im][in], 0, 0, 0);
    }

    const float scale = 0.08838834764831845f;
    float mloc[4][4];
#pragma unroll
    for (int im = 0; im < 4; ++im)
#pragma unroll
        for (int r = 0; r < 4; ++r) {
            float m = acc[im][0][r];
#pragma unroll
            for (int in = 1; in < 4; ++in) m = fmaxf(m, acc[im][in][r]);
            mloc[im][r] = m;
        }
#pragma unroll
    for (int mask = 1; mask < 16; mask <<= 1)
#pragma unroll
        for (int im = 0; im < 4; ++im)
#pragma unroll
            for (int r = 0; r < 4; ++r)
                mloc[im][r] = fmaxf(mloc[im][r], __shfl_xor(mloc[im][r], mask, 64));
    if (l15 == 0) {
#pragma unroll
        for (int im = 0; im < 4; ++im)
#pragma unroll
            for (int r = 0; r < 4; ++r)
                redm[nh * 128 + mh * 64 + im * 16 + quad * 4 + r] = mloc[im][r];
    }
    __syncthreads();
    float sloc[4][4];
#pragma unroll
    for (int im = 0; im < 4; ++im)
#pragma unroll
        for (int r = 0; r < 4; ++r) {
            int row = mh * 64 + im * 16 + quad * 4 + r;
            float m = fmaxf(redm[row], redm[128 + row]);
            float ss = 0.f;
#pragma unroll
            for (int in = 0; in < 4; ++in) {
                float e = __expf((acc[im][in][r] - m) * scale);
                acc[im][in][r] = e;
                ss += e;
            }
            sloc[im][r] = ss;
        }
#pragma unroll
    for (int mask = 1; mask < 16; mask <<= 1)
#pragma unroll
        for (int im = 0; im < 4; ++im)
#pragma unroll
            for (int r = 0; r < 4; ++r)
                sloc[im][r] += __shfl_xor(sloc[im][r], mask, 64);
    if (l15 == 0) {
#pragma unroll
        for (int im = 0; im < 4; ++im)
#pragma unroll
            for (int r = 0; r < 4; ++r)
                reds[nh * 128 + mh * 64 + im * 16 + quad * 4 + r] = sloc[im][r];
    }
    __syncthreads();
#pragma unroll
    for (int im = 0; im < 4; ++im)
#pragma unroll
        for (int r = 0; r < 4; ++r) {
            int row = mh * 64 + im * 16 + quad * 4 + r;
            float inv = 1.0f / (reds[row] + reds[128 + row]);
#pragma unroll
            for (int in = 0; in < 4; ++in) {
                int col = nh * 64 + in * 16 + l15;
                Pb[row * 136 + col] = f2bf(acc[im][in][r] * inv);
            }
        }
    __syncthreads();

    // ---- Phase 2: O = P·v  (A=Pb, B=vT swizzled) ----
#pragma unroll
    for (int im = 0; im < 4; ++im)
#pragma unroll
        for (int in = 0; in < 4; ++in)
            acc[im][in] = (floatx4){0.f, 0.f, 0.f, 0.f};
#pragma unroll
    for (int kc = 0; kc < 128; kc += 32) {
        short8 af[4], bf_[4];
#pragma unroll
        for (int im = 0; im < 4; ++im)
            af[im] = *reinterpret_cast<const short8*>(
                &Pb[(mh * 64 + im * 16 + l15) * 136 + kc + quad * 8]);
#pragma unroll
        for (int in = 0; in < 4; ++in) {
            int dRow = nh * 64 + in * 16 + l15;
            int cphys = (((kc >> 3) + quad) ^ (dRow >> 3)) & 15;
            bf_[in] = *reinterpret_cast<const short8*>(
                &vT[dRow * 136 + cphys * 8]);
        }
#pragma unroll
        for (int im = 0; im < 4; ++im)
#pragma unroll
            for (int in = 0; in < 4; ++in)
                acc[im][in] = __builtin_amdgcn_mfma_f32_16x16x32_bf16(
                    af[im], bf_[in], acc[im][in], 0, 0, 0);
    }
    __syncthreads();
#pragma unroll
    for (int im = 0; im < 4; ++im)
#pragma unroll
        for (int in = 0; in < 4; ++in) {
            int col = nh * 64 + in * 16 + l15;
#pragma unroll
            for (int r = 0; r < 4; ++r) {
                int row = mh * 64 + im * 16 + quad * 4 + r;
                Pb[row * 136 + col] = f2bf(acc[im][in][r]);
            }
        }
    __syncthreads();

    // ---- Phase 3: Y = O·WoT + bo ----
    float bb[4];
#pragma unroll
    for (int in = 0; in < 4; ++in) bb[in] = bo[nh * 64 + in * 16 + l15];
#pragma unroll
    for (int im = 0; im < 4; ++im)
#pragma unroll
        for (int in = 0; in < 4; ++in)
            acc[im][in] = (floatx4){0.f, 0.f, 0.f, 0.f};
#pragma unroll
    for (int kc = 0; kc < 128; kc += 32) {
        short8 af[4], bf_[4];
#pragma unroll
        for (int im = 0; im < 4; ++im)
            af[im] = *reinterpret_cast<const short8*>(
                &Pb[(mh * 64 + im * 16 + l15) * 136 + kc + quad * 8]);
#pragma unroll
        for (int in = 0; in < 4; ++in)
            bf_[in] = *reinterpret_cast<const short8*>(
                WoB + (nh * 64 + in * 16 + l15) * 128 + kc + quad * 8);
#pragma unroll
        for (int im = 0; im < 4; ++im)
#pragma unroll
            for (int in = 0; in < 4; ++in)
                acc[im][in] = __builtin_amdgcn_mfma_f32_16x16x32_bf16(
                    af[im], bf_[in], acc[im][in], 0, 0, 0);
    }
#pragma unroll
    for (int im = 0; im < 4; ++im)
#pragma unroll
        for (int in = 0; in < 4; ++in) {
            int col = nh * 64 + in * 16 + l15;
#pragma unroll
            for (int r = 0; r < 4; ++r) {
                int row = mh * 64 + im * 16 + quad * 4 + r;
                outp[hb + (size_t)row * 128 + col] = acc[im][in][r] + bb[in];
            }
        }
}

// ---------------------------------------------------------------------------
extern "C" void kernel_launch(void* const* d_in, const int* in_sizes, int n_in,
                              void* d_out, int out_size, void* d_ws, size_t ws_size,
                              hipStream_t stream) {
    const float* x   = (const float*)d_in[0];
    const float* Wq  = (const float*)d_in[2];
    const float* bq  = (const float*)d_in[3];
    const float* Wk  = (const float*)d_in[4];
    const float* bk  = (const float*)d_in[5];
    const float* Wv  = (const float*)d_in[6];
    const float* bv  = (const float*)d_in[7];
    const float* Wo  = (const float*)d_in[8];
    const float* bo  = (const float*)d_in[9];
    const float* Wc1 = (const float*)d_in[10];
    const float* bc1 = (const float*)d_in[11];
    const float* Wc2 = (const float*)d_in[12];
    const float* rel = (const float*)d_in[13];

    char* wsb = (char*)d_ws;
    short* q_bf  = (short*)(wsb);                       // 16 MB
    short* k_bf  = (short*)(wsb + 1ull * 16777216);
    short* v_bf  = (short*)(wsb + 2ull * 16777216);
    short* x_bf  = (short*)(wsb + 3ull * 16777216);
    float* P     = (float*)(wsb + 4ull * 16777216);     // 13.1 MB
    float* W2    = (float*)(wsb + 4ull * 16777216 + 13107200);
    float* cst   = W2 + 6400;
    float* b_eff = cst + 64;
    short* wbf   = (short*)(b_eff + 16);                // 4 x 16384 bf16
    float* outp  = (float*)d_out;

    hipLaunchKernelGGL(k_wprep,  dim3(82),   dim3(256), 0, stream, Wc1, Wc2, bc1, Wq, bq,
                       Wk, Wv, Wo, W2, cst, b_eff, wbf);
    hipLaunchKernelGGL(k_off,    dim3(1024), dim3(256), 0, stream, x, W2, cst, P, x_bf);
    hipLaunchKernelGGL(k_fused3, dim3(512),  dim3(256), 0, stream, P, b_eff, x_bf, wbf,
                       bq, bk, bv, rel, q_bf, k_bf, v_bf);
    hipLaunchKernelGGL(k_attn3,  dim3(512),  dim3(256), 0, stream, q_bf, k_bf, v_bf,
                       wbf + 49152, bo, outp);
}